// Round 6
// baseline (462.515 us; speedup 1.0000x reference)
//
#include <hip/hip_runtime.h>
#include <hip/hip_bf16.h>

#define COMMA_IDC 1010
#define NHEAD 8
#define Ll 511
#define Mrows 32704
#define NSEG 17

typedef __attribute__((ext_vector_type(8))) short bf16x8;
typedef __attribute__((ext_vector_type(4))) float f32x4;
typedef unsigned short u16;
typedef unsigned int u32;
typedef unsigned long long u64;

__device__ __forceinline__ u16 f2b(float f) {
  __hip_bfloat16 h = __float2bfloat16(f);
  return *reinterpret_cast<u16*>(&h);
}
__device__ __forceinline__ float b2f(u16 u) {
  u32 x = ((u32)u) << 16;
  return __builtin_bit_cast(float, x);
}

__device__ __forceinline__ void gld_lds16(const void* g, void* l) {
  __builtin_amdgcn_global_load_lds(
      (const __attribute__((address_space(1))) void*)(u64)g,
      (__attribute__((address_space(3))) void*)(u32)(u64)l,
      16, 0, 0);
}

#define MFMA16(a, b, c) __builtin_amdgcn_mfma_f32_16x16x32_bf16(a, b, c, 0, 0, 0)
#define LGKM0 do { asm volatile("s_waitcnt lgkmcnt(0)" ::: "memory"); __builtin_amdgcn_sched_barrier(0); } while (0)

// ---- all 4 weight matrices to bf16 in one launch: wq|wk|wv -> wqkvb, wo -> wob
__global__ void conv_w(const float4* __restrict__ wq, const float4* __restrict__ wk,
                       const float4* __restrict__ wv, const float4* __restrict__ wo,
                       ushort4* __restrict__ wqkvb, ushort4* __restrict__ wob) {
  int i = blockIdx.x * 256 + threadIdx.x;
  int seg = i / 147456, off = i - seg * 147456;
  const float4* s = (seg == 0) ? wq : ((seg == 1) ? wk : ((seg == 2) ? wv : wo));
  ushort4* d = (seg == 3) ? wob : (wqkvb + seg * 147456);
  float4 v = s[off];
  ushort4 o; o.x = f2b(v.x); o.y = f2b(v.y); o.z = f2b(v.z); o.w = f2b(v.w);
  d[off] = o;
}

__global__ void zero_kernel(float* p, int n) {
  int i = blockIdx.x * 256 + threadIdx.x;
  if (i < n) p[i] = 0.f;
}

// ============ 256x256x(K=768) bf16 MFMA GEMM, 2-phase, W-reg-cached ============
// C = A @ W^T + bias, out [m][NOUT] bf16. W [N][768] bf16 row-major.
// AF32: A inputs are f32 [.][512][768]; GEMM row m maps to src row m + m/511 + 1
//       (token-0 slicing folded in). A reg-staged (load f32 -> cvt -> swizzled
//       ds_write); W via gld_lds (pre-swizzled source). Counted vmcnt(8) keeps
//       next-next A loads in flight across the tile boundary.
// !AF32: A bf16 via gld_lds like W.
// DO_STATS: fused per-column sum/sumsq atomics (rows m < Mrows only).
#define LDA(db, i, kk) (*(const bf16x8*)(sMem + (db) + wr * 8192 + ((i) * 16 + fr) * 64 + ((((kk) * 4 + fq) ^ xm) << 3)))
#define LDW(db, j, kk) (*(const bf16x8*)(sMem + (db) + 16384 + (((wc * 64 + (j) * 16) >> 7) * 8192) + \
                     (((wc * 64 + (j) * 16) & 127) + fr) * 64 + ((((kk) * 4 + fq) ^ xm) << 3)))

template<int NTILES, int NOUT, int QNT, bool AF32, bool DO_STATS>
__global__ __launch_bounds__(512, 2) void gemm256(
    const void* __restrict__ A0v, const void* __restrict__ A1v, const u16* __restrict__ W,
    const float* __restrict__ b0, const float* __restrict__ b1, const float* __restrict__ b2,
    u16* __restrict__ outp, float* __restrict__ ssum, float* __restrict__ ssq)
{
  __shared__ __align__(16) u16 sMem[65536];  // 128 KB: [buf][A 16K u16 | W 16K u16]
  const int tid = threadIdx.x;
  const int lane = tid & 63, wid = tid >> 6;
  const int fr = lane & 15, fq = lane >> 4;
  const int wr = wid >> 2, wc = wid & 3;
  const int xm = fr & 7;

  int fid = blockIdx.x;
  int xcd = fid & 7, w = fid >> 3;
  int mrow = xcd * 16 + w / NTILES;
  int ncol = w - (w / NTILES) * NTILES;
  const int m0 = mrow * 256, n0 = ncol * 256;

  // W staging source (pre-swizzled): LDS pos (row,p) holds global chunk p^(row&7)
  const int rS = tid >> 3;
  const int cS = (tid & 7) ^ (rS & 7);
  const u16* gW0 = W + (u64)(n0 + rS) * 768 + cS * 8;
  const u16* gW1 = W + (u64)(n0 + 128 + rS) * 768 + cS * 8;
  const u32 st0 = tid * 8;

  // A staging setup
  const float* fA = (ncol < QNT) ? (const float*)A0v : (const float*)A1v;
  const u16*   uA = (ncol < QNT) ? (const u16*)A0v : (const u16*)A1v;
  const float* aSrc[4];
  u32 aDst[4];
  if constexpr (AF32) {
#pragma unroll
    for (int c4 = 0; c4 < 4; c4++) {
      int c = tid + c4 * 512;
      int half = c >> 10, rowin = (c >> 3) & 127, p = c & 7;
      int m = m0 + half * 128 + rowin;
      if (m > Mrows - 1) m = Mrows - 1;          // clamp: avoid OOB input read
      int srcrow = m + m / 511 + 1;              // token-0 slice fold-in
      int s = p ^ (rowin & 7);
      aSrc[c4] = fA + (u64)srcrow * 768 + s * 8;
      aDst[c4] = (u32)(half * 8192 + rowin * 64 + p * 8);
    }
  }
  const u16* gA0u = nullptr;
  const u16* gA1u = nullptr;
  if constexpr (!AF32) {
    gA0u = uA + (u64)(m0 + rS) * 768 + cS * 8;
    gA1u = uA + (u64)(m0 + 128 + rS) * 768 + cS * 8;
  }

  f32x4 acc[8][4] = {};
  bf16x8 af[4][2], wf[4][2];
  float4 rA[8];

  auto stageW = [&](int buf, int kt) {
    const int kb = kt * 64;
    const u32 db = (u32)buf * 32768 + 16384;
    gld_lds16(gW0 + kb, sMem + db + st0);
    gld_lds16(gW0 + kb + 49152, sMem + db + st0 + 4096);
    gld_lds16(gW1 + kb, sMem + db + 8192 + st0);
    gld_lds16(gW1 + kb + 49152, sMem + db + 8192 + st0 + 4096);
  };
  auto stageAu = [&](int buf, int kt) {
    const int kb = kt * 64;
    const u32 db = (u32)buf * 32768;
    gld_lds16(gA0u + kb, sMem + db + st0);
    gld_lds16(gA0u + kb + 49152, sMem + db + st0 + 4096);
    gld_lds16(gA1u + kb, sMem + db + 8192 + st0);
    gld_lds16(gA1u + kb + 49152, sMem + db + 8192 + st0 + 4096);
  };
  auto loadA = [&](int kt) {
#pragma unroll
    for (int c4 = 0; c4 < 4; c4++) {
      rA[2 * c4]     = *(const float4*)(aSrc[c4] + kt * 64);
      rA[2 * c4 + 1] = *(const float4*)(aSrc[c4] + kt * 64 + 4);
    }
  };
  auto writeA = [&](int buf) {
    const u32 db = (u32)buf * 32768;
#pragma unroll
    for (int c4 = 0; c4 < 4; c4++) {
      const float4 x = rA[2 * c4], y = rA[2 * c4 + 1];
      bf16x8 v;
      v[0] = (short)f2b(x.x); v[1] = (short)f2b(x.y); v[2] = (short)f2b(x.z); v[3] = (short)f2b(x.w);
      v[4] = (short)f2b(y.x); v[5] = (short)f2b(y.y); v[6] = (short)f2b(y.z); v[7] = (short)f2b(y.w);
      *(bf16x8*)(sMem + db + aDst[c4]) = v;
    }
  };

  // ---- prologue
  if constexpr (AF32) {
    stageW(0, 0);
    loadA(0);
    writeA(0);        // reg-dep wait also drains W(0) (vmcnt in-order)
    loadA(1);
  } else {
    stageAu(0, 0);
    stageW(0, 0);
    asm volatile("s_waitcnt vmcnt(0)" ::: "memory");
  }
  LGKM0;
  __builtin_amdgcn_s_barrier();

  for (int kt = 0; kt < 12; ++kt) {
    const u32 db = (u32)(kt & 1) * 32768;
    // ---- phase 0: frag reads (A-lo + W all) | stage tile kt+1 | MFMA lo-half
#pragma unroll
    for (int i = 0; i < 4; i++) { af[i][0] = LDA(db, i, 0); af[i][1] = LDA(db, i, 1); }
#pragma unroll
    for (int j = 0; j < 4; j++) { wf[j][0] = LDW(db, j, 0); wf[j][1] = LDW(db, j, 1); }
    if (kt + 1 < 12) {
      if constexpr (AF32) {
        writeA((kt + 1) & 1);               // buf^1 safe: its last read ended at kt-1's end barrier
        stageW((kt + 1) & 1, kt + 1);       // W first (drained by vmcnt(8))
        if (kt + 2 < 12) loadA(kt + 2);     // stays in flight across tile boundary
      } else {
        stageAu((kt + 1) & 1, kt + 1);
        stageW((kt + 1) & 1, kt + 1);
      }
    }
    __builtin_amdgcn_s_barrier();
    LGKM0;
    __builtin_amdgcn_s_setprio(1);
#pragma unroll
    for (int i = 0; i < 4; i++)
#pragma unroll
      for (int j = 0; j < 4; j++) {
        acc[i][j] = MFMA16(af[i][0], wf[j][0], acc[i][j]);
        acc[i][j] = MFMA16(af[i][1], wf[j][1], acc[i][j]);
      }
    __builtin_amdgcn_s_setprio(0);
    __builtin_amdgcn_s_barrier();
    // ---- phase 1: frag reads (A-hi) | MFMA hi-half | drain staging | tile-end barrier
#pragma unroll
    for (int i = 0; i < 4; i++) { af[i][0] = LDA(db, i + 4, 0); af[i][1] = LDA(db, i + 4, 1); }
    LGKM0;
    __builtin_amdgcn_s_setprio(1);
#pragma unroll
    for (int i = 0; i < 4; i++)
#pragma unroll
      for (int j = 0; j < 4; j++) {
        acc[i + 4][j] = MFMA16(af[i][0], wf[j][0], acc[i + 4][j]);
        acc[i + 4][j] = MFMA16(af[i][1], wf[j][1], acc[i + 4][j]);
      }
    __builtin_amdgcn_s_setprio(0);
    if (kt + 1 < 12) {
      if constexpr (AF32) {
        if (kt + 2 < 12) { asm volatile("s_waitcnt vmcnt(8)" ::: "memory"); }  // drain W(kt+1), keep A(kt+2)
        else             { asm volatile("s_waitcnt vmcnt(0)" ::: "memory"); }
      } else {
        asm volatile("s_waitcnt vmcnt(0)" ::: "memory");
      }
    }
    __builtin_amdgcn_s_barrier();
  }

  // bias for this block's 256-col slice (768-col segment)
  const float* bp = (n0 < 768) ? b0 : ((n0 < 1536) ? b1 : b2);
  const int bcol = n0 % 768;
  float bj[4];
#pragma unroll
  for (int j = 0; j < 4; j++) bj[j] = bp[bcol + wc * 64 + j * 16 + fr];

  // ---- fused channel stats (gemm2 only): sum / sumsq per column, f32, valid rows only
  if constexpr (DO_STATS) {
#pragma unroll
    for (int j = 0; j < 4; j++) {
      float s = 0.f, q = 0.f;
#pragma unroll
      for (int i = 0; i < 8; i++)
#pragma unroll
        for (int r = 0; r < 4; r++) {
          int m = m0 + wr * 128 + i * 16 + fq * 4 + r;
          float v = acc[i][j][r] + bj[j];
          if (m < Mrows) { s += v; q += v * v; }
        }
      s += __shfl_xor(s, 16, 64); s += __shfl_xor(s, 32, 64);
      q += __shfl_xor(q, 16, 64); q += __shfl_xor(q, 32, 64);
      if (fq == 0) {
        int col = n0 + wc * 64 + j * 16 + fr;
        atomicAdd(&ssum[col], s);
        atomicAdd(&ssq[col], q);
      }
    }
  }

  // epilogue: acc -> LDS (stride 264) -> coalesced bf16x8 stores, 2 halves of 128 rows
#pragma unroll
  for (int h = 0; h < 2; h++) {
    __syncthreads();
    if (wr == h) {
#pragma unroll
      for (int i = 0; i < 8; i++)
#pragma unroll
        for (int j = 0; j < 4; j++)
#pragma unroll
          for (int r = 0; r < 4; r++)
            sMem[(i * 16 + fq * 4 + r) * 264 + wc * 64 + j * 16 + fr] = f2b(acc[i][j][r] + bj[j]);
    }
    __syncthreads();
#pragma unroll
    for (int it = 0; it < 8; it++) {
      int chunk = tid + it * 512;
      int lr = chunk >> 5, ch = chunk & 31;
      *(bf16x8*)(outp + (u64)(m0 + h * 128 + lr) * NOUT + n0 + ch * 8) =
          *(const bf16x8*)(sMem + lr * 264 + ch * 8);
    }
  }
}

// ---- V transpose: QKV[m][2304] V-cols -> VT [b,h,96,512], XOR-swizzled LDS tile
__global__ __launch_bounds__(256) void vtrans(const u16* __restrict__ QKV, u16* __restrict__ VT) {
  __shared__ __align__(16) u16 sT[128 * 128];
  int bh = blockIdx.y;
  int b = bh >> 3, h = bh & 7;
  int l0 = blockIdx.x * 128;
  u16* outp = VT + (u64)bh * 96 * 512;
  int t = threadIdx.x;
#pragma unroll
  for (int k = 0; k < 6; k++) {
    int c = t + k * 256;
    int l = c / 12, ch = c - l * 12;
    int lc = l0 + l; if (lc > 510) lc = 510;
    bf16x8 v = *(const bf16x8*)(QKV + (u64)(b * 511 + lc) * 2304 + 1536 + h * 96 + ch * 8);
    int chunk = l * 16 + (ch ^ ((l >> 3) & 7));
    *(bf16x8*)(sT + chunk * 8) = v;
  }
  __syncthreads();
#pragma unroll
  for (int k = 0; k < 6; k++) {
    int c = t + k * 256;
    int d = c >> 4, lch = c & 15;
    u16 vals[8];
#pragma unroll
    for (int k2 = 0; k2 < 8; k2++) {
      int r = lch * 8 + k2;
      int idx = r * 128 + (((d >> 3) ^ (lch & 7)) << 3) + (d & 7);
      vals[k2] = sT[idx];
    }
    bf16x8 o;
#pragma unroll
    for (int k2 = 0; k2 < 8; k2++) o[k2] = (short)vals[k2];
    *(bf16x8*)(outp + (u64)d * 512 + l0 + lch * 8) = o;
  }
}

// ---- flash attention, fixed-max softmax. Block = 128 q rows, 4 waves x 32 q, KVBLK=64.
// K tile: rotation-swizzled chunks (2-way banks); V tile from VT with chunk-XOR swizzle.
#define PST 68
__global__ __launch_bounds__(256) void attn_kernel(
    const u16* __restrict__ QKV, const u16* __restrict__ VT, u16* __restrict__ ctxb)
{
  __shared__ __align__(16) u16 sK[64 * 96];
  __shared__ __align__(16) u16 sV[96 * 64];
  __shared__ __align__(16) u16 sP[4][16 * PST];
  const int tid = threadIdx.x, lane = tid & 63, wid = tid >> 6;
  int fid = blockIdx.x;
  int xcd = fid & 7, slot = (fid >> 3) & 3, grp = fid >> 5;
  int bh = grp * 8 + xcd;
  int b = bh >> 3, h = bh & 7;
  int q0 = slot * 128;
  const int fr = lane & 15, fq = lane >> 4;
  const u64 mb = (u64)(b * 511);
  const u64 hbV = (u64)bh * 96 * 512;

  bf16x8 qf[2][3];
#pragma unroll
  for (int sub = 0; sub < 2; sub++) {
    int qr = q0 + wid * 32 + sub * 16 + fr; if (qr > 510) qr = 510;
#pragma unroll
    for (int ks = 0; ks < 3; ks++)
      qf[sub][ks] = *(const bf16x8*)(QKV + (mb + qr) * 2304 + h * 96 + ks * 32 + fq * 8);
  }

  f32x4 ctx[2][6] = {};
  f32x4 sumP[2] = {};

  // staging: 3 K + 3 V 16B-chunks per thread; wave-uniform LDS dest, per-lane source
  int kRow[3]; u32 kOffG[3], vOffG[3];
  u16 *kDst[3], *vDst[3];
#pragma unroll
  for (int k = 0; k < 3; k++) {
    int c = wid * 64 + lane + k * 256;
    // K: LDS pos (r,p) holds global chunk (p - r) mod 12  -> read addr r*12 + (s+r)%12
    int r = c / 12, p = c - r * 12;
    int s = p - (r % 12); if (s < 0) s += 12;
    kRow[k] = r;
    kOffG[k] = 768 + h * 96 + s * 8;
    kDst[k] = sK + (u32)(wid * 64 + k * 256) * 8;
    // V: LDS pos (d,p) holds global chunk p^(d&7)
    int d = c >> 3, pv = c & 7;
    int sv = pv ^ (d & 7);
    vOffG[k] = (u32)(d * 512 + sv * 8);
    vDst[k] = sV + (u32)(wid * 64 + k * 256) * 8;
  }

  const float cs = 0.10206207261596575f; // 1/sqrt(96)
  u16* pw = &sP[wid][0];

  for (int kv0 = 0; kv0 < 511; kv0 += 64) {
    __syncthreads();
#pragma unroll
    for (int k = 0; k < 3; k++) {
      int row = kv0 + kRow[k]; if (row > 510) row = 510;
      gld_lds16(QKV + (mb + row) * 2304 + kOffG[k], kDst[k]);
    }
#pragma unroll
    for (int k = 0; k < 3; k++)
      gld_lds16(VT + hbV + vOffG[k] + kv0, vDst[k]);
    __syncthreads();

    // K fragments: rotation-swizzled read
    bf16x8 kf[4][3];
#pragma unroll
    for (int kv16 = 0; kv16 < 4; kv16++) {
      int r = kv16 * 16 + fr;
      int rm = r % 12;
#pragma unroll
      for (int ks = 0; ks < 3; ks++) {
        int sidx = ks * 4 + fq + rm; if (sidx >= 12) sidx -= 12;
        kf[kv16][ks] = *(const bf16x8*)(sK + (r * 12 + sidx) * 8);
      }
    }

#pragma unroll
    for (int sub = 0; sub < 2; sub++) {
      f32x4 s[4] = {};
#pragma unroll
      for (int kv16 = 0; kv16 < 4; kv16++)
#pragma unroll
        for (int ks = 0; ks < 3; ks++)
          s[kv16] = MFMA16(qf[sub][ks], kf[kv16][ks], s[kv16]);

#pragma unroll
      for (int kv16 = 0; kv16 < 4; kv16++) {
        bool ok = (kv0 + kv16 * 16 + fr) < Ll;
#pragma unroll
        for (int r = 0; r < 4; r++) {
          float e = __expf(s[kv16][r] * cs);
          e = ok ? e : 0.f;
          sumP[sub][r] += e;
          pw[(fq * 4 + r) * PST + kv16 * 16 + fr] = f2b(e);
        }
      }
      bf16x8 pf0 = *(const bf16x8*)(pw + fr * PST + fq * 8);
      bf16x8 pf1 = *(const bf16x8*)(pw + fr * PST + 32 + fq * 8);
#pragma unroll
      for (int df = 0; df < 6; df++) {
        int row = df * 16 + fr;
        int xv = fr & 7;
        bf16x8 vf0 = *(const bf16x8*)(sV + row * 64 + ((fq ^ xv) << 3));
        bf16x8 vf1 = *(const bf16x8*)(sV + row * 64 + (((4 + fq) ^ xv) << 3));
        ctx[sub][df] = MFMA16(pf0, vf0, ctx[sub][df]);
        ctx[sub][df] = MFMA16(pf1, vf1, ctx[sub][df]);
      }
    }
  }

#pragma unroll
  for (int sub = 0; sub < 2; sub++) {
    float inv[4];
#pragma unroll
    for (int r = 0; r < 4; r++) {
      float s = sumP[sub][r];
      s += __shfl_xor(s, 1, 64);
      s += __shfl_xor(s, 2, 64);
      s += __shfl_xor(s, 4, 64);
      s += __shfl_xor(s, 8, 64);
      inv[r] = 1.f / s;
    }
#pragma unroll
    for (int df = 0; df < 6; df++) {
#pragma unroll
      for (int r = 0; r < 4; r++) {
        int q = q0 + wid * 32 + sub * 16 + fq * 4 + r;
        if (q < Ll)
          ctxb[(u64)(b * Ll + q) * 768 + h * 96 + df * 16 + fr] = f2b(ctx[sub][df][r] * inv[r]);
      }
    }
  }
}

__global__ __launch_bounds__(256) void derived_kernel(
    const float* __restrict__ ssum, const float* __restrict__ ssq,
    const float* __restrict__ w_out, const float* __restrict__ b_out,
    const float* __restrict__ gamma, const float* __restrict__ beta,
    float* __restrict__ weff, float* __restrict__ consts)
{
  __shared__ float red[256];
  int t = threadIdx.x;
  float acc = 0.f;
  const float invN = 1.f / 32704.f;
#pragma unroll
  for (int i = 0; i < 3; i++) {
    int hh = t + i * 256;
    float mu = ssum[hh] * invN;
    float var = ssq[hh] * invN - mu * mu;
    float rstd = 1.f / sqrtf(var + 1e-5f);
    float we = w_out[hh] * gamma[hh] * rstd;
    weff[hh] = we;
    acc += w_out[hh] * beta[hh] - we * mu;
  }
  red[t] = acc; __syncthreads();
  for (int s = 128; s > 0; s >>= 1) { if (t < s) red[t] += red[t + s]; __syncthreads(); }
  if (t == 0) consts[0] = b_out[0] + red[0];
}

// ---- fv[m] = dot(c_row_f32, w_out) + dot(a_row_bf16, weff) + const  (one wave per row)
__global__ __launch_bounds__(256) void fv_kernel(
    const u16* __restrict__ ao, const float* __restrict__ cols,
    const float* __restrict__ w_out, const float* __restrict__ weff,
    const float* __restrict__ consts, float* __restrict__ fv)
{
  int lane = threadIdx.x & 63, wid = threadIdx.x >> 6;
  int m = blockIdx.x * 4 + wid;
  if (m >= Mrows) return;
  int bidx = m / 511, l = m - bidx * 511;
  const u16* ap = ao + (u64)m * 768;
  const float* cp = cols + (u64)(bidx * 512 + l + 1) * 768;
  float acc = 0.f;
#pragma unroll
  for (int i = 0; i < 12; i++) {
    int hh = lane + i * 64;
    acc += b2f(ap[hh]) * weff[hh] + cp[hh] * w_out[hh];
  }
#pragma unroll
  for (int off = 1; off < 64; off <<= 1) acc += __shfl_xor(acc, off, 64);
  if (lane == 0) fv[m] = acc + consts[0];
}

// ---- comma-delimited segment means, one wave per batch row
__global__ __launch_bounds__(64) void seg_kernel(
    const float* __restrict__ fv, const int* __restrict__ ids, float* __restrict__ out)
{
  __shared__ float ssum[NSEG];
  __shared__ int scnt[NSEG];
  int lane = threadIdx.x;
  int b = blockIdx.x;
  if (lane < NSEG) { ssum[lane] = 0.f; scnt[lane] = 0; }
  __syncthreads();
  int carry = 0;
  for (int it = 0; it < 8; it++) {
    int l = it * 64 + lane;
    bool active = l < Ll;
    int id = active ? ids[b * 512 + l] : 0;
    bool comma = active && (id == COMMA_IDC);
    u64 cmask = __ballot(comma);
    int seg = carry + __popcll(cmask & ((1ull << lane) - 1ull));
    bool valid = active && (l >= 1) && !comma;
    if (valid && seg < NSEG) {
      atomicAdd(&ssum[seg], fv[b * Ll + l]);
      atomicAdd(&scnt[seg], 1);
    }
    carry += __popcll(cmask);
  }
  __syncthreads();
  if (lane < NSEG) {
    float c = (float)scnt[lane];
    out[b * NSEG + lane] = ssum[lane] / fmaxf(c, 1.f);
  }
}

extern "C" void kernel_launch(void* const* d_in, const int* in_sizes, int n_in,
                              void* d_out, int out_size, void* d_ws, size_t ws_size,
                              hipStream_t stream)
{
  const float* text  = (const float*)d_in[0];
  const float* cols  = (const float*)d_in[1];
  const float* wq    = (const float*)d_in[2];
  const float* wk    = (const float*)d_in[3];
  const float* wvp   = (const float*)d_in[4];
  const float* bq    = (const float*)d_in[5];
  const float* bk    = (const float*)d_in[6];
  const float* bv    = (const float*)d_in[7];
  const float* wo    = (const float*)d_in[8];
  const float* bo    = (const float*)d_in[9];
  const float* gamma = (const float*)d_in[10];
  const float* beta  = (const float*)d_in[11];
  const float* w_out = (const float*)d_in[12];
  const float* b_out = (const float*)d_in[13];
  const int*   ids   = (const int*)d_in[14];
  float* out = (float*)d_out;

  char* ws = (char*)d_ws;
  u16* VTb   = (u16*)(ws + 0ull);              // [512][96][512] bf16
  u16* wqkvb = (u16*)(ws + 50331648ull);       // [2304][768] bf16
  u16* wob   = (u16*)(ws + 53870592ull);       // [768][768] bf16
  float* ssum   = (float*)(ws + 55050240ull);
  float* ssq    = ssum + 768;
  float* weff   = ssum + 1536;
  float* consts = ssum + 2304;
  float* fv     = (float*)(ws + 55050240ull + 16384ull);
  u16* QKVb  = (u16*)(ws + 56623104ull);       // [32768][2304] bf16; aob reuses after attn
  u16* ctxb  = (u16*)(ws + 207618048ull);      // [32768][768] bf16 (attn out)
  u16* aob   = QKVb;                            // [32768][768] bf16 (gemm2 out)

  conv_w<<<2304, 256, 0, stream>>>(
      (const float4*)wq, (const float4*)wk, (const float4*)wvp, (const float4*)wo,
      (ushort4*)wqkvb, (ushort4*)wob);
  zero_kernel<<<6, 256, 0, stream>>>(ssum, 1536);

  // QKV: A read directly from f32 inputs (slicing folded in); n-tiles 0-2 cols(Q), 3-8 text(K,V)
  gemm256<9, 2304, 3, true, false><<<1152, 512, 0, stream>>>(
      cols, text, wqkvb, bq, bk, bv, QKVb, nullptr, nullptr);
  vtrans<<<dim3(4, 512), 256, 0, stream>>>(QKVb, VTb);
  attn_kernel<<<2048, 256, 0, stream>>>(QKVb, VTb, ctxb);

  // out-projection + fused channel stats
  gemm256<3, 768, 99, false, true><<<384, 512, 0, stream>>>(
      ctxb, ctxb, wob, bo, bo, bo, aob, ssum, ssq);
  derived_kernel<<<1, 256, 0, stream>>>(ssum, ssq, w_out, b_out, gamma, beta, weff, consts);
  fv_kernel<<<8176, 256, 0, stream>>>(aob, cols, w_out, weff, consts, fv);
  seg_kernel<<<64, 64, 0, stream>>>(fv, ids, out);
}

// Round 7
// 412.665 us; speedup vs baseline: 1.1208x; 1.1208x over previous
//
#include <hip/hip_runtime.h>
#include <hip/hip_bf16.h>

#define COMMA_IDC 1010
#define NHEAD 8
#define Ll 511
#define Mrows 32704
#define NSEG 17

typedef __attribute__((ext_vector_type(8))) short bf16x8;
typedef __attribute__((ext_vector_type(4))) float f32x4;
typedef unsigned short u16;
typedef unsigned int u32;
typedef unsigned long long u64;

__device__ __forceinline__ u16 f2b(float f) {
  __hip_bfloat16 h = __float2bfloat16(f);
  return *reinterpret_cast<u16*>(&h);
}
__device__ __forceinline__ float b2f(u16 u) {
  u32 x = ((u32)u) << 16;
  return __builtin_bit_cast(float, x);
}

__device__ __forceinline__ void gld_lds16(const void* g, void* l) {
  __builtin_amdgcn_global_load_lds(
      (const __attribute__((address_space(1))) void*)(u64)g,
      (__attribute__((address_space(3))) void*)(u32)(u64)l,
      16, 0, 0);
}

#define MFMA16(a, b, c) __builtin_amdgcn_mfma_f32_16x16x32_bf16(a, b, c, 0, 0, 0)
#define LGKM0 do { asm volatile("s_waitcnt lgkmcnt(0)" ::: "memory"); __builtin_amdgcn_sched_barrier(0); } while (0)
#define VMC(n) asm volatile("s_waitcnt vmcnt(" #n ")" ::: "memory")

// ---- convert f32 -> bf16, slicing off token 0; z=0: cols->cb, z=1: text->tb
__global__ void conv_sliced2(const float4* __restrict__ s0, const float4* __restrict__ s1,
                             ushort4* __restrict__ d0, ushort4* __restrict__ d1) {
  const float4* src = blockIdx.z ? s1 : s0;
  ushort4* dst = blockIdx.z ? d1 : d0;
  int b = blockIdx.y;
  int idx = blockIdx.x * 256 + threadIdx.x;
  if (idx >= Ll * 192) return;
  int l = idx / 192, c = idx - l * 192;
  float4 v = src[(b * 512 + l + 1) * 192 + c];
  ushort4 o; o.x = f2b(v.x); o.y = f2b(v.y); o.z = f2b(v.z); o.w = f2b(v.w);
  dst[(b * Ll + l) * 192 + c] = o;
}

// ---- all 4 weight matrices in one launch: wq|wk|wv -> wqkvb, wo -> wob
__global__ void conv_w(const float4* __restrict__ wq, const float4* __restrict__ wk,
                       const float4* __restrict__ wv, const float4* __restrict__ wo,
                       ushort4* __restrict__ wqkvb, ushort4* __restrict__ wob) {
  int i = blockIdx.x * 256 + threadIdx.x;
  int seg = i / 147456, off = i - seg * 147456;
  const float4* s = (seg == 0) ? wq : ((seg == 1) ? wk : ((seg == 2) ? wv : wo));
  ushort4* d = (seg == 3) ? wob : (wqkvb + seg * 147456);
  float4 v = s[off];
  ushort4 o; o.x = f2b(v.x); o.y = f2b(v.y); o.z = f2b(v.z); o.w = f2b(v.w);
  d[off] = o;
}

__global__ void zero_kernel(float* p, int n) {
  int i = blockIdx.x * 256 + threadIdx.x;
  if (i < n) p[i] = 0.f;
}

// ============ 256x256x(K=768) bf16 GEMM, m201-style 4-phase counted-vmcnt ============
// C = A @ W^T + bias, out [m][NOUT] bf16. W [N][768] bf16 row-major.
// 512 thr / 8 waves. Wave rows INTERLEAVED: A row(i)=i*32+wr*16+fr, W col(j)=j*64+wc*16+fr
// -> every wave's phase-p frags come from the same staged half (uniform dependency).
// Per K-tile: 4 phases, each {ds_read frags | stage 1 half (2 gld_lds) | barrier |
// lgkmcnt(0) | 16 MFMA}; vmcnt(4) at phase ends 0/1/3 (ledger-proved, never full drain).
#define LDA8(db, i, kk) (*(const bf16x8*)(sMem + (db) + ((i) * 32 + wr * 16 + fr) * 64 + ((((kk) * 4 + fq) ^ xm) << 3)))
#define LDW8(db, j, kk) (*(const bf16x8*)(sMem + (db) + 16384 + ((j) * 64 + wc * 16 + fr) * 64 + ((((kk) * 4 + fq) ^ xm) << 3)))

template<int NTILES, int NOUT, int QNT, bool DO_STATS>
__global__ __launch_bounds__(512, 2) void gemm256(
    const u16* __restrict__ A0, const u16* __restrict__ A1, const u16* __restrict__ W,
    const float* __restrict__ b0, const float* __restrict__ b1, const float* __restrict__ b2,
    u16* __restrict__ outp, float* __restrict__ ssum, float* __restrict__ ssq)
{
  __shared__ __align__(16) u16 sMem[65536];  // 128 KB: [buf][A 16K u16 | W 16K u16]
  const int tid = threadIdx.x;
  const int lane = tid & 63, wid = tid >> 6;
  const int fr = lane & 15, fq = lane >> 4;
  const int wr = wid >> 2, wc = wid & 3;
  const int xm = fr & 7;

  int fid = blockIdx.x;
  int xcd = fid & 7, w = fid >> 3;
  int mrow = xcd * 16 + w / NTILES;
  int ncol = w - (w / NTILES) * NTILES;
  const int m0 = mrow * 256, n0 = ncol * 256;
  const u16* __restrict__ A = (ncol < QNT) ? A0 : A1;

  // staging: LDS (row,p) holds global chunk p^(row&7); linear dest, pre-swizzled source
  const int rS = tid >> 3;
  const int cS = (tid & 7) ^ (rS & 7);
  const u16* gA0 = A + (u64)(m0 + rS) * 768 + cS * 8;
  const u16* gW0 = W + (u64)(n0 + rS) * 768 + cS * 8;
  const u32 st0 = tid * 8;

  auto stALO = [&](u32 db, int kb) {
    gld_lds16(gA0 + kb, sMem + db + st0);
    gld_lds16(gA0 + kb + 49152, sMem + db + st0 + 4096);
  };
  auto stWLO = [&](u32 db, int kb) {
    gld_lds16(gW0 + kb, sMem + db + 16384 + st0);
    gld_lds16(gW0 + kb + 49152, sMem + db + 16384 + st0 + 4096);
  };
  auto stAHI = [&](u32 db, int kb) {
    gld_lds16(gA0 + kb + 98304, sMem + db + 8192 + st0);
    gld_lds16(gA0 + kb + 147456, sMem + db + 8192 + st0 + 4096);
  };
  auto stWHI = [&](u32 db, int kb) {
    gld_lds16(gW0 + kb + 98304, sMem + db + 24576 + st0);
    gld_lds16(gW0 + kb + 147456, sMem + db + 24576 + st0 + 4096);
  };

  f32x4 acc[8][4] = {};
  bf16x8 af[4][2], wl[2][2], wh[2][2];

  // prologue: tile 0, stage order ALO,WLO,AHI,WHI; retire ALO+WLO
  stALO(0, 0); stWLO(0, 0); stAHI(0, 0); stWHI(0, 0);
  VMC(4);
  __builtin_amdgcn_s_barrier();

#pragma unroll 1
  for (int kt = 0; kt < 11; ++kt) {
    const u32 db = (u32)(kt & 1) * 32768;
    const u32 nb = db ^ 32768u;
    const int kb1 = (kt + 1) * 64;

    // ---- ph0: frags A-lo + W-lo | stage A-lo(kt+1) | MFMA (i0-3, j0-1)
#pragma unroll
    for (int i = 0; i < 4; i++) { af[i][0] = LDA8(db, i, 0); af[i][1] = LDA8(db, i, 1); }
#pragma unroll
    for (int j = 0; j < 2; j++) { wl[j][0] = LDW8(db, j, 0); wl[j][1] = LDW8(db, j, 1); }
    stALO(nb, kb1);
    __builtin_amdgcn_s_barrier();
    LGKM0;
    __builtin_amdgcn_s_setprio(1);
#pragma unroll
    for (int i = 0; i < 4; i++)
#pragma unroll
      for (int j = 0; j < 2; j++) {
        acc[i][j] = MFMA16(af[i][0], wl[j][0], acc[i][j]);
        acc[i][j] = MFMA16(af[i][1], wl[j][1], acc[i][j]);
      }
    __builtin_amdgcn_s_setprio(0);
    VMC(4);                       // retire A-hi(kt)
    __builtin_amdgcn_s_barrier();

    // ---- ph1: frags A-hi | stage W-lo(kt+1) | MFMA (i4-7, j0-1)
#pragma unroll
    for (int i = 0; i < 4; i++) { af[i][0] = LDA8(db, i + 4, 0); af[i][1] = LDA8(db, i + 4, 1); }
    stWLO(nb, kb1);
    __builtin_amdgcn_s_barrier();
    LGKM0;
    __builtin_amdgcn_s_setprio(1);
#pragma unroll
    for (int i = 0; i < 4; i++)
#pragma unroll
      for (int j = 0; j < 2; j++) {
        acc[i + 4][j] = MFMA16(af[i][0], wl[j][0], acc[i + 4][j]);
        acc[i + 4][j] = MFMA16(af[i][1], wl[j][1], acc[i + 4][j]);
      }
    __builtin_amdgcn_s_setprio(0);
    VMC(4);                       // retire W-hi(kt)
    __builtin_amdgcn_s_barrier();

    // ---- ph2: frags W-hi | stage A-hi(kt+1) | MFMA (i4-7, j2-3)
#pragma unroll
    for (int j = 0; j < 2; j++) { wh[j][0] = LDW8(db, j + 2, 0); wh[j][1] = LDW8(db, j + 2, 1); }
    stAHI(nb, kb1);
    __builtin_amdgcn_s_barrier();
    LGKM0;
    __builtin_amdgcn_s_setprio(1);
#pragma unroll
    for (int i = 0; i < 4; i++)
#pragma unroll
      for (int j = 0; j < 2; j++) {
        acc[i + 4][j + 2] = MFMA16(af[i][0], wh[j][0], acc[i + 4][j + 2]);
        acc[i + 4][j + 2] = MFMA16(af[i][1], wh[j][1], acc[i + 4][j + 2]);
      }
    __builtin_amdgcn_s_setprio(0);
    __builtin_amdgcn_s_barrier();

    // ---- ph3: frags A-lo (re-read) | stage W-hi(kt+1) | MFMA (i0-3, j2-3)
#pragma unroll
    for (int i = 0; i < 4; i++) { af[i][0] = LDA8(db, i, 0); af[i][1] = LDA8(db, i, 1); }
    stWHI(nb, kb1);
    __builtin_amdgcn_s_barrier();
    LGKM0;
    __builtin_amdgcn_s_setprio(1);
#pragma unroll
    for (int i = 0; i < 4; i++)
#pragma unroll
      for (int j = 0; j < 2; j++) {
        acc[i][j + 2] = MFMA16(af[i][0], wh[j][0], acc[i][j + 2]);
        acc[i][j + 2] = MFMA16(af[i][1], wh[j][1], acc[i][j + 2]);
      }
    __builtin_amdgcn_s_setprio(0);
    VMC(4);                       // retire A-lo+W-lo(kt+1): invariant for next ph0
    __builtin_amdgcn_s_barrier();
  }

  // ---- peeled tile 11 (db = 32768, no staging)
  {
    const u32 db = 32768u;
#pragma unroll
    for (int i = 0; i < 4; i++) { af[i][0] = LDA8(db, i, 0); af[i][1] = LDA8(db, i, 1); }
#pragma unroll
    for (int j = 0; j < 2; j++) { wl[j][0] = LDW8(db, j, 0); wl[j][1] = LDW8(db, j, 1); }
    __builtin_amdgcn_s_barrier();
    LGKM0;
#pragma unroll
    for (int i = 0; i < 4; i++)
#pragma unroll
      for (int j = 0; j < 2; j++) {
        acc[i][j] = MFMA16(af[i][0], wl[j][0], acc[i][j]);
        acc[i][j] = MFMA16(af[i][1], wl[j][1], acc[i][j]);
      }
    VMC(2);                       // retire A-hi(11)
    __builtin_amdgcn_s_barrier();
#pragma unroll
    for (int i = 0; i < 4; i++) { af[i][0] = LDA8(db, i + 4, 0); af[i][1] = LDA8(db, i + 4, 1); }
    __builtin_amdgcn_s_barrier();
    LGKM0;
#pragma unroll
    for (int i = 0; i < 4; i++)
#pragma unroll
      for (int j = 0; j < 2; j++) {
        acc[i + 4][j] = MFMA16(af[i][0], wl[j][0], acc[i + 4][j]);
        acc[i + 4][j] = MFMA16(af[i][1], wl[j][1], acc[i + 4][j]);
      }
    VMC(0);                       // retire W-hi(11)
    __builtin_amdgcn_s_barrier();
#pragma unroll
    for (int j = 0; j < 2; j++) { wh[j][0] = LDW8(db, j + 2, 0); wh[j][1] = LDW8(db, j + 2, 1); }
    LGKM0;
#pragma unroll
    for (int i = 0; i < 4; i++)
#pragma unroll
      for (int j = 0; j < 2; j++) {
        acc[i + 4][j + 2] = MFMA16(af[i][0], wh[j][0], acc[i + 4][j + 2]);
        acc[i + 4][j + 2] = MFMA16(af[i][1], wh[j][1], acc[i + 4][j + 2]);
      }
#pragma unroll
    for (int i = 0; i < 4; i++) { af[i][0] = LDA8(db, i, 0); af[i][1] = LDA8(db, i, 1); }
    LGKM0;
#pragma unroll
    for (int i = 0; i < 4; i++)
#pragma unroll
      for (int j = 0; j < 2; j++) {
        acc[i][j + 2] = MFMA16(af[i][0], wh[j][0], acc[i][j + 2]);
        acc[i][j + 2] = MFMA16(af[i][1], wh[j][1], acc[i][j + 2]);
      }
  }

  // bias: col(j) = n0 + j*64 + wc*16 + fr
  const float* bp = (n0 < 768) ? b0 : ((n0 < 1536) ? b1 : b2);
  const int bcol = n0 % 768;
  float bj[4];
#pragma unroll
  for (int j = 0; j < 4; j++) bj[j] = bp[bcol + j * 64 + wc * 16 + fr];

  // fused channel stats (gemm2 only): m(i,r) = m0 + i*32 + wr*16 + fq*4 + r
  if constexpr (DO_STATS) {
#pragma unroll
    for (int j = 0; j < 4; j++) {
      float s = 0.f, q = 0.f;
#pragma unroll
      for (int i = 0; i < 8; i++)
#pragma unroll
        for (int r = 0; r < 4; r++) {
          int m = m0 + i * 32 + wr * 16 + fq * 4 + r;
          float v = acc[i][j][r] + bj[j];
          if (m < Mrows) { s += v; q += v * v; }
        }
      s += __shfl_xor(s, 16, 64); s += __shfl_xor(s, 32, 64);
      q += __shfl_xor(q, 16, 64); q += __shfl_xor(q, 32, 64);
      if (fq == 0) {
        int col = n0 + j * 64 + wc * 16 + fr;
        atomicAdd(&ssum[col], s);
        atomicAdd(&ssq[col], q);
      }
    }
  }

  // epilogue: acc -> LDS (stride 264) -> coalesced bf16x8 stores; halves are i<4 / i>=4
#pragma unroll
  for (int h = 0; h < 2; h++) {
    __syncthreads();
#pragma unroll
    for (int i2 = 0; i2 < 4; i2++) {
      int i = h * 4 + i2;
#pragma unroll
      for (int j = 0; j < 4; j++)
#pragma unroll
        for (int r = 0; r < 4; r++)
          sMem[(i2 * 32 + wr * 16 + fq * 4 + r) * 264 + j * 64 + wc * 16 + fr] =
              f2b(acc[i][j][r] + bj[j]);
    }
    __syncthreads();
#pragma unroll
    for (int it = 0; it < 8; it++) {
      int chunk = tid + it * 512;
      int lr = chunk >> 5, ch = chunk & 31;
      *(bf16x8*)(outp + (u64)(m0 + h * 128 + lr) * NOUT + n0 + ch * 8) =
          *(const bf16x8*)(sMem + lr * 264 + ch * 8);
    }
  }
}

// ---- V transpose: QKV[m][2304] V-cols -> VT [b,h,96,512], XOR-swizzled LDS tile
__global__ __launch_bounds__(256) void vtrans(const u16* __restrict__ QKV, u16* __restrict__ VT) {
  __shared__ __align__(16) u16 sT[128 * 128];
  int bh = blockIdx.y;
  int b = bh >> 3, h = bh & 7;
  int l0 = blockIdx.x * 128;
  u16* outp = VT + (u64)bh * 96 * 512;
  int t = threadIdx.x;
#pragma unroll
  for (int k = 0; k < 6; k++) {
    int c = t + k * 256;
    int l = c / 12, ch = c - l * 12;
    int lc = l0 + l; if (lc > 510) lc = 510;
    bf16x8 v = *(const bf16x8*)(QKV + (u64)(b * 511 + lc) * 2304 + 1536 + h * 96 + ch * 8);
    int chunk = l * 16 + (ch ^ ((l >> 3) & 7));
    *(bf16x8*)(sT + chunk * 8) = v;
  }
  __syncthreads();
#pragma unroll
  for (int k = 0; k < 6; k++) {
    int c = t + k * 256;
    int d = c >> 4, lch = c & 15;
    u16 vals[8];
#pragma unroll
    for (int k2 = 0; k2 < 8; k2++) {
      int r = lch * 8 + k2;
      int idx = r * 128 + (((d >> 3) ^ (lch & 7)) << 3) + (d & 7);
      vals[k2] = sT[idx];
    }
    bf16x8 o;
#pragma unroll
    for (int k2 = 0; k2 < 8; k2++) o[k2] = (short)vals[k2];
    *(bf16x8*)(outp + (u64)d * 512 + l0 + lch * 8) = o;
  }
}

// ---- flash attention, fixed-max softmax. Block = 128 q rows, 4 waves x 32 q, KVBLK=64.
#define PST 68
__global__ __launch_bounds__(256) void attn_kernel(
    const u16* __restrict__ QKV, const u16* __restrict__ VT, u16* __restrict__ ctxb)
{
  __shared__ __align__(16) u16 sK[64 * 96];
  __shared__ __align__(16) u16 sV[96 * 64];
  __shared__ __align__(16) u16 sP[4][16 * PST];
  const int tid = threadIdx.x, lane = tid & 63, wid = tid >> 6;
  int fid = blockIdx.x;
  int xcd = fid & 7, slot = (fid >> 3) & 3, grp = fid >> 5;
  int bh = grp * 8 + xcd;
  int b = bh >> 3, h = bh & 7;
  int q0 = slot * 128;
  const int fr = lane & 15, fq = lane >> 4;
  const u64 mb = (u64)(b * 511);
  const u64 hbV = (u64)bh * 96 * 512;

  bf16x8 qf[2][3];
#pragma unroll
  for (int sub = 0; sub < 2; sub++) {
    int qr = q0 + wid * 32 + sub * 16 + fr; if (qr > 510) qr = 510;
#pragma unroll
    for (int ks = 0; ks < 3; ks++)
      qf[sub][ks] = *(const bf16x8*)(QKV + (mb + qr) * 2304 + h * 96 + ks * 32 + fq * 8);
  }

  f32x4 ctx[2][6] = {};
  f32x4 sumP[2] = {};

  int kRow[3]; u32 kOffG[3], vOffG[3];
  u16 *kDst[3], *vDst[3];
#pragma unroll
  for (int k = 0; k < 3; k++) {
    int c = wid * 64 + lane + k * 256;
    int r = c / 12, p = c - r * 12;
    int s = p - (r % 12); if (s < 0) s += 12;
    kRow[k] = r;
    kOffG[k] = 768 + h * 96 + s * 8;
    kDst[k] = sK + (u32)(wid * 64 + k * 256) * 8;
    int d = c >> 3, pv = c & 7;
    int sv = pv ^ (d & 7);
    vOffG[k] = (u32)(d * 512 + sv * 8);
    vDst[k] = sV + (u32)(wid * 64 + k * 256) * 8;
  }

  const float cs = 0.10206207261596575f; // 1/sqrt(96)
  u16* pw = &sP[wid][0];

  for (int kv0 = 0; kv0 < 511; kv0 += 64) {
    __syncthreads();
#pragma unroll
    for (int k = 0; k < 3; k++) {
      int row = kv0 + kRow[k]; if (row > 510) row = 510;
      gld_lds16(QKV + (mb + row) * 2304 + kOffG[k], kDst[k]);
    }
#pragma unroll
    for (int k = 0; k < 3; k++)
      gld_lds16(VT + hbV + vOffG[k] + kv0, vDst[k]);
    __syncthreads();

    bf16x8 kf[4][3];
#pragma unroll
    for (int kv16 = 0; kv16 < 4; kv16++) {
      int r = kv16 * 16 + fr;
      int rm = r % 12;
#pragma unroll
      for (int ks = 0; ks < 3; ks++) {
        int sidx = ks * 4 + fq + rm; if (sidx >= 12) sidx -= 12;
        kf[kv16][ks] = *(const bf16x8*)(sK + (r * 12 + sidx) * 8);
      }
    }

#pragma unroll
    for (int sub = 0; sub < 2; sub++) {
      f32x4 s[4] = {};
#pragma unroll
      for (int kv16 = 0; kv16 < 4; kv16++)
#pragma unroll
        for (int ks = 0; ks < 3; ks++)
          s[kv16] = MFMA16(qf[sub][ks], kf[kv16][ks], s[kv16]);

#pragma unroll
      for (int kv16 = 0; kv16 < 4; kv16++) {
        bool ok = (kv0 + kv16 * 16 + fr) < Ll;
#pragma unroll
        for (int r = 0; r < 4; r++) {
          float e = __expf(s[kv16][r] * cs);
          e = ok ? e : 0.f;
          sumP[sub][r] += e;
          pw[(fq * 4 + r) * PST + kv16 * 16 + fr] = f2b(e);
        }
      }
      bf16x8 pf0 = *(const bf16x8*)(pw + fr * PST + fq * 8);
      bf16x8 pf1 = *(const bf16x8*)(pw + fr * PST + 32 + fq * 8);
#pragma unroll
      for (int df = 0; df < 6; df++) {
        int row = df * 16 + fr;
        int xv = fr & 7;
        bf16x8 vf0 = *(const bf16x8*)(sV + row * 64 + ((fq ^ xv) << 3));
        bf16x8 vf1 = *(const bf16x8*)(sV + row * 64 + (((4 + fq) ^ xv) << 3));
        ctx[sub][df] = MFMA16(pf0, vf0, ctx[sub][df]);
        ctx[sub][df] = MFMA16(pf1, vf1, ctx[sub][df]);
      }
    }
  }

#pragma unroll
  for (int sub = 0; sub < 2; sub++) {
    float inv[4];
#pragma unroll
    for (int r = 0; r < 4; r++) {
      float s = sumP[sub][r];
      s += __shfl_xor(s, 1, 64);
      s += __shfl_xor(s, 2, 64);
      s += __shfl_xor(s, 4, 64);
      s += __shfl_xor(s, 8, 64);
      inv[r] = 1.f / s;
    }
#pragma unroll
    for (int df = 0; df < 6; df++) {
#pragma unroll
      for (int r = 0; r < 4; r++) {
        int q = q0 + wid * 32 + sub * 16 + fq * 4 + r;
        if (q < Ll)
          ctxb[(u64)(b * Ll + q) * 768 + h * 96 + df * 16 + fr] = f2b(ctx[sub][df][r] * inv[r]);
      }
    }
  }
}

__global__ __launch_bounds__(256) void derived_kernel(
    const float* __restrict__ ssum, const float* __restrict__ ssq,
    const float* __restrict__ w_out, const float* __restrict__ b_out,
    const float* __restrict__ gamma, const float* __restrict__ beta,
    float* __restrict__ weff, float* __restrict__ consts)
{
  __shared__ float red[256];
  int t = threadIdx.x;
  float acc = 0.f;
  const float invN = 1.f / 32704.f;
#pragma unroll
  for (int i = 0; i < 3; i++) {
    int hh = t + i * 256;
    float mu = ssum[hh] * invN;
    float var = ssq[hh] * invN - mu * mu;
    float rstd = 1.f / sqrtf(var + 1e-5f);
    float we = w_out[hh] * gamma[hh] * rstd;
    weff[hh] = we;
    acc += w_out[hh] * beta[hh] - we * mu;
  }
  red[t] = acc; __syncthreads();
  for (int s = 128; s > 0; s >>= 1) { if (t < s) red[t] += red[t + s]; __syncthreads(); }
  if (t == 0) consts[0] = b_out[0] + red[0];
}

// ---- fv[m] = dot(c_row, w_out) + dot(a_row, weff) + const   (one wave per row)
__global__ __launch_bounds__(256) void fv_kernel(
    const u16* __restrict__ ao, const u16* __restrict__ cb,
    const float* __restrict__ w_out, const float* __restrict__ weff,
    const float* __restrict__ consts, float* __restrict__ fv)
{
  int lane = threadIdx.x & 63, wid = threadIdx.x >> 6;
  int m = blockIdx.x * 4 + wid;
  if (m >= Mrows) return;
  const u16* ap = ao + (u64)m * 768;
  const u16* cp = cb + (u64)m * 768;
  float acc = 0.f;
#pragma unroll
  for (int i = 0; i < 12; i++) {
    int hh = lane + i * 64;
    acc += b2f(ap[hh]) * weff[hh] + b2f(cp[hh]) * w_out[hh];
  }
#pragma unroll
  for (int off = 1; off < 64; off <<= 1) acc += __shfl_xor(acc, off, 64);
  if (lane == 0) fv[m] = acc + consts[0];
}

// ---- comma-delimited segment means, one wave per batch row
__global__ __launch_bounds__(64) void seg_kernel(
    const float* __restrict__ fv, const int* __restrict__ ids, float* __restrict__ out)
{
  __shared__ float ssum[NSEG];
  __shared__ int scnt[NSEG];
  int lane = threadIdx.x;
  int b = blockIdx.x;
  if (lane < NSEG) { ssum[lane] = 0.f; scnt[lane] = 0; }
  __syncthreads();
  int carry = 0;
  for (int it = 0; it < 8; it++) {
    int l = it * 64 + lane;
    bool active = l < Ll;
    int id = active ? ids[b * 512 + l] : 0;
    bool comma = active && (id == COMMA_IDC);
    u64 cmask = __ballot(comma);
    int seg = carry + __popcll(cmask & ((1ull << lane) - 1ull));
    bool valid = active && (l >= 1) && !comma;
    if (valid && seg < NSEG) {
      atomicAdd(&ssum[seg], fv[b * Ll + l]);
      atomicAdd(&scnt[seg], 1);
    }
    carry += __popcll(cmask);
  }
  __syncthreads();
  if (lane < NSEG) {
    float c = (float)scnt[lane];
    out[b * NSEG + lane] = ssum[lane] / fmaxf(c, 1.f);
  }
}

extern "C" void kernel_launch(void* const* d_in, const int* in_sizes, int n_in,
                              void* d_out, int out_size, void* d_ws, size_t ws_size,
                              hipStream_t stream)
{
  const float* text  = (const float*)d_in[0];
  const float* cols  = (const float*)d_in[1];
  const float* wq    = (const float*)d_in[2];
  const float* wk    = (const float*)d_in[3];
  const float* wvp   = (const float*)d_in[4];
  const float* bq    = (const float*)d_in[5];
  const float* bk    = (const float*)d_in[6];
  const float* bv    = (const float*)d_in[7];
  const float* wo    = (const float*)d_in[8];
  const float* bo    = (const float*)d_in[9];
  const float* gamma = (const float*)d_in[10];
  const float* beta  = (const float*)d_in[11];
  const float* w_out = (const float*)d_in[12];
  const float* b_out = (const float*)d_in[13];
  const int*   ids   = (const int*)d_in[14];
  float* out = (float*)d_out;

  char* ws = (char*)d_ws;
  u16* cb    = (u16*)(ws + 0ull);             // [32768][768] bf16 (sliced cols), live till fv
  u16* tb    = (u16*)(ws + 50331648ull);      // [32768][768] bf16; VTb reuses after QKV gemm
  u16* wqkvb = (u16*)(ws + 100663296ull);     // [2304][768] bf16
  u16* wob   = (u16*)(ws + 104202240ull);     // [768][768] bf16
  u16* QKVb  = (u16*)(ws + 105381888ull);     // [32768][2304] bf16; aob + stats reuse after attn
  u16* ctxb  = (u16*)(ws + 256376832ull);     // [32768][768] bf16 (attn out)
  u16* VTb   = tb;
  u16* aob   = QKVb;
  float* ssum   = (float*)(ws + 105381888ull + 50331648ull);  // QKV K-region, dead after attn
  float* ssq    = ssum + 768;
  float* weff   = ssum + 1536;
  float* consts = ssum + 2304;
  float* fv     = (float*)((char*)ssum + 16384ull);

  conv_sliced2<<<dim3(384, 64, 2), 256, 0, stream>>>(
      (const float4*)cols, (const float4*)text, (ushort4*)cb, (ushort4*)tb);
  conv_w<<<2304, 256, 0, stream>>>(
      (const float4*)wq, (const float4*)wk, (const float4*)wvp, (const float4*)wo,
      (ushort4*)wqkvb, (ushort4*)wob);

  // QKV: out [m][2304]; n-tiles 0-2 use cb (Q), 3-8 use tb (K,V)
  gemm256<9, 2304, 3, false><<<1152, 512, 0, stream>>>(
      cb, tb, wqkvb, bq, bk, bv, QKVb, nullptr, nullptr);
  vtrans<<<dim3(4, 512), 256, 0, stream>>>(QKVb, VTb);
  attn_kernel<<<2048, 256, 0, stream>>>(QKVb, VTb, ctxb);

  zero_kernel<<<6, 256, 0, stream>>>(ssum, 1536);
  gemm256<3, 768, 99, true><<<384, 512, 0, stream>>>(
      ctxb, ctxb, wob, bo, bo, bo, aob, ssum, ssq);
  derived_kernel<<<1, 256, 0, stream>>>(ssum, ssq, w_out, b_out, gamma, beta, weff, consts);
  fv_kernel<<<8176, 256, 0, stream>>>(aob, cb, w_out, weff, consts, fv);
  seg_kernel<<<64, 64, 0, stream>>>(fv, ids, out);
}